// Round 9
// baseline (329.696 us; speedup 1.0000x reference)
//
#include <hip/hip_runtime.h>

typedef unsigned short u16;
typedef unsigned int   u32;
using short8 = __attribute__((ext_vector_type(8))) short;
using f32x4  = __attribute__((ext_vector_type(4))) float;
using f32x16 = __attribute__((ext_vector_type(16))) float;
using u32x4  = __attribute__((ext_vector_type(4))) unsigned int;

#define S_LEN 4096
#define EMB   768
#define NH    12
#define DH    64

// 0.125 (=1/sqrt(64)) * log2(e): folded into Q so softmax uses exp2 directly
#define QSCALE 0.18033688011112042f

__device__ __forceinline__ u16 f2bf(float f) {
  unsigned int u = __builtin_bit_cast(unsigned int, f);
  u += 0x7fffu + ((u >> 16) & 1u);
  return (u16)(u >> 16);
}

__device__ __forceinline__ u32 cvtpk(float lo, float hi) {
  u32 r;
  asm("v_cvt_pk_bf16_f32 %0, %1, %2" : "=v"(r) : "v"(lo), "v"(hi));
  return r;
}

// Cross-half (lane ^ 32) combines -- PROVEN primitive (R3/R6 passed).
// Raw v_permlane32_swap asm failed both orientations (R4/R5); do not use.
// Struct-copy register pipelining spilled to scratch (R7, rule #20); do not use.
__device__ __forceinline__ float pr_max(float v) {
  return fmaxf(v, __shfl_xor(v, 32));
}
__device__ __forceinline__ float pr_add(float v) {
  return v + __shfl_xor(v, 32);
}

__device__ __forceinline__ float fexp2(float x) {
#if __has_builtin(__builtin_amdgcn_exp2f)
  return __builtin_amdgcn_exp2f(x);
#else
  return exp2f(x);
#endif
}

__device__ __forceinline__ f32x4 mfma16(short8 a, short8 b, f32x4 c) {
  return __builtin_amdgcn_mfma_f32_16x16x32_bf16(a, b, c, 0, 0, 0);
}
__device__ __forceinline__ f32x16 mfma32(short8 a, short8 b, f32x16 c) {
  return __builtin_amdgcn_mfma_f32_32x32x16_bf16(a, b, c, 0, 0, 0);
}

// pack 8 f32 P-values into one PV B-frag (k-slice), R3-proven mapping:
//   lower lane: {own w0, own w1, partner w0, partner w1}
//   upper lane: {partner w2, partner w3, own w2, own w3}
__device__ __forceinline__ short8 pack_frag(u32 w0, u32 w1, u32 w2, u32 w3, bool hi) {
  u32 x0 = (u32)__shfl_xor((int)w0, 32), x1 = (u32)__shfl_xor((int)w1, 32);
  u32 x2 = (u32)__shfl_xor((int)w2, 32), x3 = (u32)__shfl_xor((int)w3, 32);
  u32x4 f = { hi ? x2 : w0, hi ? x3 : w1, hi ? w2 : x0, hi ? w3 : x1 };
  return __builtin_bit_cast(short8, f);
}

// ---------------- conversion / transpose kernels ----------------

__global__ void k_conv_x(const float* __restrict__ x, u16* __restrict__ xb, int n) {
  int i = blockIdx.x * 256 + threadIdx.x;
  if (i < n) xb[i] = f2bf(x[i]);
}

__global__ __launch_bounds__(256) void k_transpose_w(const float* __restrict__ w,
                                                     u16* __restrict__ wt,
                                                     int rows, int cols) {
  __shared__ float tile[32][33];
  int tx = threadIdx.x & 31, ty = threadIdx.x >> 5;
  int kb = blockIdx.x * 32;
  int nb = blockIdx.y * 32;
#pragma unroll
  for (int j = 0; j < 4; j++)
    tile[ty + 8 * j][tx] = w[(size_t)(kb + ty + 8 * j) * cols + nb + tx];
  __syncthreads();
#pragma unroll
  for (int j = 0; j < 4; j++)
    wt[(size_t)(nb + ty + 8 * j) * rows + kb + tx] = f2bf(tile[tx][ty + 8 * j]);
}

// ---------------- QKV GEMM + bias + RoPE epilogue ----------------
__global__ __launch_bounds__(256) void k_qkv(const u16* __restrict__ A,
                                             const u16* __restrict__ Bt,
                                             const float* __restrict__ bias,
                                             u16* __restrict__ Qb,
                                             u16* __restrict__ Kb,
                                             u16* __restrict__ Vt) {
  __shared__ u16 As[128][40];
  __shared__ u16 Bs[128][40];
  int t = threadIdx.x;
  int w = t >> 6, lane = t & 63, g = lane >> 4, c = lane & 15;
  int wr = w >> 1, wc = w & 1;
  int bm = blockIdx.x * 128, bn = blockIdx.y * 128;

  f32x4 acc[4][4];
#pragma unroll
  for (int m = 0; m < 4; m++)
#pragma unroll
    for (int n = 0; n < 4; n++) acc[m][n] = (f32x4){0.f, 0.f, 0.f, 0.f};

  int srow = t >> 1, sseg = (t & 1) * 16;
  for (int bk = 0; bk < EMB; bk += 32) {
    const u16* ga = A  + (size_t)(bm + srow) * EMB + bk + sseg;
    const u16* gb = Bt + (size_t)(bn + srow) * EMB + bk + sseg;
    short8 a0 = *(const short8*)ga, a1 = *(const short8*)(ga + 8);
    short8 b0 = *(const short8*)gb, b1 = *(const short8*)(gb + 8);
    __syncthreads();
    *(short8*)&As[srow][sseg] = a0; *(short8*)&As[srow][sseg + 8] = a1;
    *(short8*)&Bs[srow][sseg] = b0; *(short8*)&Bs[srow][sseg + 8] = b1;
    __syncthreads();
    short8 af[4], bf[4];
#pragma unroll
    for (int m = 0; m < 4; m++) af[m] = *(const short8*)&As[wr * 64 + m * 16 + c][g * 8];
#pragma unroll
    for (int n = 0; n < 4; n++) bf[n] = *(const short8*)&Bs[wc * 64 + n * 16 + c][g * 8];
#pragma unroll
    for (int m = 0; m < 4; m++)
#pragma unroll
      for (int n = 0; n < 4; n++) acc[m][n] = mfma16(af[m], bf[n], acc[m][n]);
  }

  int colbase = bn + wc * 64;
  int sec = colbase / EMB;               // 0=Q 1=K 2=V
  int hh  = (colbase % EMB) / DH;
  float qs = (sec == 0) ? QSCALE : 1.0f;
  float invf[2];
#pragma unroll
  for (int n = 0; n < 2; n++) {
    int d1 = n * 16 + c;
    invf[n] = exp2f(-(float)d1 * (13.287712379549449f / 32.0f));
  }
#pragma unroll
  for (int m = 0; m < 4; m++) {
    int rowb = bm + wr * 64 + m * 16 + 4 * g;
#pragma unroll
    for (int e = 0; e < 4; e++) {
      int srw = rowb + e;
      float v[4];
#pragma unroll
      for (int n = 0; n < 4; n++) v[n] = acc[m][n][e] + bias[colbase + n * 16 + c];
      if (sec == 2) {
#pragma unroll
        for (int n = 0; n < 4; n++)
          Vt[(size_t)(hh * DH + n * 16 + c) * S_LEN + srw] = f2bf(v[n]);
      } else {
        u16* dst = (sec == 0) ? Qb : Kb;
        size_t base = ((size_t)hh * S_LEN + srw) * DH;
#pragma unroll
        for (int n = 0; n < 2; n++) {
          int d1 = n * 16 + c;
          float ang = (float)srw * invf[n];
          float sn, cs;
          sincosf(ang, &sn, &cs);
          float o1 = (v[n] * cs - v[n + 2] * sn) * qs;
          float o2 = (v[n + 2] * cs + v[n] * sn) * qs;
          dst[base + d1]      = f2bf(o1);
          dst[base + d1 + 32] = f2bf(o2);
        }
      }
    }
  }
}

// ---------------- flash attention ----------------
// Complementary-pair blocks: block owns q-blocks {pi, 127-pi} of one head ->
// every block has exactly 129 tile-computations (perfect balance), and on the
// shared KV region t<=pi one K/V load feeds BOTH q-sets (load amortization).
// 4 waves split the union KV range by cumulative work units.

__device__ __forceinline__ f32x16 qk4(short8 k0, short8 k1, short8 k2, short8 k3,
                                      short8 q0, short8 q1, short8 q2, short8 q3) {
  f32x16 sc = {0,0,0,0,0,0,0,0,0,0,0,0,0,0,0,0};
  __builtin_amdgcn_s_setprio(1);
  sc = mfma32(k0, q0, sc);
  sc = mfma32(k1, q1, sc);
  sc = mfma32(k2, q2, sc);
  sc = mfma32(k3, q3, sc);
  __builtin_amdgcn_s_setprio(0);
  return sc;
}

__device__ __forceinline__ void finish_set(f32x16 sc, bool masked, int qi, int half,
    short8 v0, short8 v1, short8 v2, short8 v3,
    f32x16& acc0, f32x16& acc1, float& m, float& l) {
  if (masked) {
#pragma unroll
    for (int i = 0; i < 16; i++) {
      int kl = (i & 3) + 8 * (i >> 2) + 4 * half;
      if (kl > qi) sc[i] = -1e30f;
    }
  }
  float t0 = fmaxf(fmaxf(sc[0], sc[1]), fmaxf(sc[2], sc[3]));
  float t1 = fmaxf(fmaxf(sc[4], sc[5]), fmaxf(sc[6], sc[7]));
  float t2 = fmaxf(fmaxf(sc[8], sc[9]), fmaxf(sc[10], sc[11]));
  float t3 = fmaxf(fmaxf(sc[12], sc[13]), fmaxf(sc[14], sc[15]));
  float rmax = pr_max(fmaxf(fmaxf(t0, t1), fmaxf(t2, t3)));
  if (__any(rmax > m + 8.0f)) {
    float mn = fmaxf(m, rmax);
    float f = fexp2(m - mn);
    m = mn; l *= f;
#pragma unroll
    for (int i = 0; i < 16; i++) { acc0[i] *= f; acc1[i] *= f; }
  }
  f32x16 p;
#pragma unroll
  for (int i = 0; i < 16; i++) p[i] = fexp2(sc[i] - m);
  l += ((p[0] + p[1]) + (p[2] + p[3])) + ((p[4] + p[5]) + (p[6] + p[7]))
     + ((p[8] + p[9]) + (p[10] + p[11])) + ((p[12] + p[13]) + (p[14] + p[15]));
  bool hi = (half != 0);
  short8 pa0 = pack_frag(cvtpk(p[0], p[1]),   cvtpk(p[2], p[3]),
                         cvtpk(p[4], p[5]),   cvtpk(p[6], p[7]), hi);
  short8 pa1 = pack_frag(cvtpk(p[8], p[9]),   cvtpk(p[10], p[11]),
                         cvtpk(p[12], p[13]), cvtpk(p[14], p[15]), hi);
  __builtin_amdgcn_s_setprio(1);
  acc0 = mfma32(v0, pa0, acc0);
  acc0 = mfma32(v1, pa1, acc0);
  acc1 = mfma32(v2, pa0, acc1);
  acc1 = mfma32(v3, pa1, acc1);
  __builtin_amdgcn_s_setprio(0);
}

__global__ __launch_bounds__(256, 2) void k_attn(const u16* __restrict__ Q,
                                                 const u16* __restrict__ K,
                                                 const u16* __restrict__ Vt,
                                                 u16* __restrict__ O) {
  __shared__ float Lacc[3][64][33];
  __shared__ float Lml[2][3][32];

  int t = threadIdx.x;
  int w = t >> 6, lane = t & 63;
  int qi = lane & 31, half = lane >> 5;
  int b = blockIdx.x;
  int h  = b % NH;
  int pi = b / NH;                    // 0..63
  int qbL = pi, qbH = 127 - pi;

  const u16* Qh = Q  + (size_t)h * S_LEN * DH;
  const u16* Kh = K  + (size_t)h * S_LEN * DH;
  const u16* Vh = Vt + (size_t)h * DH * S_LEN;

  const u16* qpL = Qh + (size_t)(qbL * 32 + qi) * DH + half * 8;
  short8 qL0 = *(const short8*)(qpL);
  short8 qL1 = *(const short8*)(qpL + 16);
  short8 qL2 = *(const short8*)(qpL + 32);
  short8 qL3 = *(const short8*)(qpL + 48);
  const u16* qpH = Qh + (size_t)(qbH * 32 + qi) * DH + half * 8;
  short8 qH0 = *(const short8*)(qpH);
  short8 qH1 = *(const short8*)(qpH + 16);
  short8 qH2 = *(const short8*)(qpH + 32);
  short8 qH3 = *(const short8*)(qpH + 48);

  f32x16 accL0 = {0,0,0,0,0,0,0,0,0,0,0,0,0,0,0,0};
  f32x16 accL1 = {0,0,0,0,0,0,0,0,0,0,0,0,0,0,0,0};
  f32x16 accH0 = {0,0,0,0,0,0,0,0,0,0,0,0,0,0,0,0};
  f32x16 accH1 = {0,0,0,0,0,0,0,0,0,0,0,0,0,0,0,0};
  float mL = -1e30f, lL = 0.f, mH = -1e30f, lH = 0.f;

  // work units: tiles t<=pi count 2 (both sets), pi<t<=127-pi count 1. total 129.
  int thr2 = 2 * (pi + 1);
  int u0 = (w * 129) >> 2;
  int u1 = ((w + 1) * 129) >> 2;
  int tw  = (u0 < thr2) ? (u0 >> 1) : (u0 - (pi + 1));
  int tw1 = (u1 < thr2) ? (u1 >> 1) : (u1 - (pi + 1));

#pragma unroll 1
  for (int tt = tw; tt < tw1; tt++) {
    int kv0 = tt * 32;
    const u16* kp = Kh + (size_t)(kv0 + qi) * DH + half * 8;
    short8 k0 = *(const short8*)(kp);
    short8 k1 = *(const short8*)(kp + 16);
    short8 k2 = *(const short8*)(kp + 32);
    short8 k3 = *(const short8*)(kp + 48);
    const u16* vp = Vh + (size_t)qi * S_LEN + kv0 + half * 8;
    short8 v0 = *(const short8*)(vp);
    short8 v1 = *(const short8*)(vp + 16);
    short8 v2 = *(const short8*)(vp + (size_t)32 * S_LEN);
    short8 v3 = *(const short8*)(vp + (size_t)32 * S_LEN + 16);
    bool doLow = (tt <= pi);
    f32x16 scH = qk4(k0, k1, k2, k3, qH0, qH1, qH2, qH3);
    if (doLow) {
      f32x16 scL = qk4(k0, k1, k2, k3, qL0, qL1, qL2, qL3);
      finish_set(scL, tt == pi, qi, half, v0, v1, v2, v3, accL0, accL1, mL, lL);
    }
    finish_set(scH, tt == qbH, qi, half, v0, v1, v2, v3, accH0, accH1, mH, lH);
  }

  // ---- merge + write set L, then set H (LDS reused) ----
#pragma unroll 1
  for (int s = 0; s < 2; s++) {
    f32x16& a0 = s ? accH0 : accL0;
    f32x16& a1 = s ? accH1 : accL1;
    float m  = s ? mH : mL;
    float l  = s ? lH : lL;
    int   qb = s ? qbH : qbL;
    float l2 = pr_add(l);
    if (s) __syncthreads();            // protect LDS reuse
    if (w > 0) {
#pragma unroll
      for (int i = 0; i < 16; i++) {
        Lacc[w - 1][lane][i]      = a0[i];
        Lacc[w - 1][lane][16 + i] = a1[i];
      }
      if (half == 0) { Lml[0][w - 1][qi] = m; Lml[1][w - 1][qi] = l2; }
    }
    __syncthreads();
    if (w == 0) {
      float mw[3], lw[3];
      float M = m;
#pragma unroll
      for (int j = 0; j < 3; j++) { mw[j] = Lml[0][j][qi]; lw[j] = Lml[1][j][qi]; M = fmaxf(M, mw[j]); }
      float f0 = fexp2(m - M);
      float ltot = l2 * f0;
      f32x16 o0, o1;
#pragma unroll
      for (int i = 0; i < 16; i++) { o0[i] = a0[i] * f0; o1[i] = a1[i] * f0; }
#pragma unroll
      for (int j = 0; j < 3; j++) {
        float fj = fexp2(mw[j] - M);
        ltot += lw[j] * fj;
#pragma unroll
        for (int i = 0; i < 16; i++) {
          o0[i] += fj * Lacc[j][lane][i];
          o1[i] += fj * Lacc[j][lane][16 + i];
        }
      }
      float rl = 1.0f / ltot;
      u16* orow = O + (size_t)(qb * 32 + qi) * EMB + h * DH;
#pragma unroll
      for (int i = 0; i < 16; i += 2) {
        int dl = (i & 3) + 8 * (i >> 2) + 4 * half;
        u32 wa = cvtpk(o0[i] * rl, o0[i + 1] * rl);
        u32 wb = cvtpk(o1[i] * rl, o1[i + 1] * rl);
        *(u32*)(orow + dl)      = wa;
        *(u32*)(orow + 32 + dl) = wb;
      }
    }
  }
}

// ---------------- output projection ----------------
__global__ __launch_bounds__(256) void k_out(const u16* __restrict__ A,
                                             const u16* __restrict__ Bt,
                                             const float* __restrict__ bias,
                                             float* __restrict__ out) {
  __shared__ u16 As[128][40];
  __shared__ u16 Bs[128][40];
  int t = threadIdx.x;
  int w = t >> 6, lane = t & 63, g = lane >> 4, c = lane & 15;
  int wr = w >> 1, wc = w & 1;
  int bm = blockIdx.x * 128, bn = blockIdx.y * 128;

  f32x4 acc[4][4];
#pragma unroll
  for (int m = 0; m < 4; m++)
#pragma unroll
    for (int n = 0; n < 4; n++) acc[m][n] = (f32x4){0.f, 0.f, 0.f, 0.f};

  int srow = t >> 1, sseg = (t & 1) * 16;
  for (int bk = 0; bk < EMB; bk += 32) {
    const u16* ga = A  + (size_t)(bm + srow) * EMB + bk + sseg;
    const u16* gb = Bt + (size_t)(bn + srow) * EMB + bk + sseg;
    short8 a0 = *(const short8*)ga, a1 = *(const short8*)(ga + 8);
    short8 b0 = *(const short8*)gb, b1 = *(const short8*)(gb + 8);
    __syncthreads();
    *(short8*)&As[srow][sseg] = a0; *(short8*)&As[srow][sseg + 8] = a1;
    *(short8*)&Bs[srow][sseg] = b0; *(short8*)&Bs[srow][sseg + 8] = b1;
    __syncthreads();
    short8 af[4], bf[4];
#pragma unroll
    for (int m = 0; m < 4; m++) af[m] = *(const short8*)&As[wr * 64 + m * 16 + c][g * 8];
#pragma unroll
    for (int n = 0; n < 4; n++) bf[n] = *(const short8*)&Bs[wc * 64 + n * 16 + c][g * 8];
#pragma unroll
    for (int m = 0; m < 4; m++)
#pragma unroll
      for (int n = 0; n < 4; n++) acc[m][n] = mfma16(af[m], bf[n], acc[m][n]);
  }
  int colbase = bn + wc * 64;
#pragma unroll
  for (int m = 0; m < 4; m++) {
    int rowb = bm + wr * 64 + m * 16 + 4 * g;
#pragma unroll
    for (int e = 0; e < 4; e++) {
      int srw = rowb + e;
#pragma unroll
      for (int n = 0; n < 4; n++) {
        int col = colbase + n * 16 + c;
        out[(size_t)srw * EMB + col] = acc[m][n][e] + bias[col];
      }
    }
  }
}

// ---------------- launcher ----------------

extern "C" void kernel_launch(void* const* d_in, const int* in_sizes, int n_in,
                              void* d_out, int out_size, void* d_ws, size_t ws_size,
                              hipStream_t stream) {
  const float* x    = (const float*)d_in[0];
  const float* Wqkv = (const float*)d_in[2];
  const float* bqkv = (const float*)d_in[3];
  const float* Wout = (const float*)d_in[4];
  const float* bout = (const float*)d_in[5];
  float* out = (float*)d_out;

  char* ws = (char*)d_ws;
  u16* xb     = (u16*)(ws);
  u16* wqkvt  = (u16*)(ws + 6291456);
  u16* woutt  = (u16*)(ws + 9830400);
  u16* Qb     = (u16*)(ws + 11010048);
  u16* Kb     = (u16*)(ws + 17301504);
  u16* Vtb    = (u16*)(ws + 23592960);
  u16* Ob     = (u16*)(ws + 29884416);

  k_conv_x<<<(S_LEN * EMB + 255) / 256, 256, 0, stream>>>(x, xb, S_LEN * EMB);
  k_transpose_w<<<dim3(EMB / 32, 3 * EMB / 32), 256, 0, stream>>>(Wqkv, wqkvt, EMB, 3 * EMB);
  k_transpose_w<<<dim3(EMB / 32, EMB / 32), 256, 0, stream>>>(Wout, woutt, EMB, EMB);

  k_qkv<<<dim3(32, 18), 256, 0, stream>>>(xb, wqkvt, bqkv, Qb, Kb, Vtb);
  k_attn<<<NH * 64, 256, 0, stream>>>(Qb, Kb, Vtb, Ob);
  k_out<<<dim3(32, 6), 256, 0, stream>>>(Ob, woutt, bout, out);
}

// Round 10
// 195.371 us; speedup vs baseline: 1.6875x; 1.6875x over previous
//
#include <hip/hip_runtime.h>

typedef unsigned short u16;
typedef unsigned int   u32;
using short8 = __attribute__((ext_vector_type(8))) short;
using f32x4  = __attribute__((ext_vector_type(4))) float;
using f32x16 = __attribute__((ext_vector_type(16))) float;
using u32x4  = __attribute__((ext_vector_type(4))) unsigned int;

#define S_LEN 4096
#define EMB   768
#define NH    12
#define DH    64

// 0.125 (=1/sqrt(64)) * log2(e): folded into Q so softmax uses exp2 directly
#define QSCALE 0.18033688011112042f

__device__ __forceinline__ u16 f2bf(float f) {
  unsigned int u = __builtin_bit_cast(unsigned int, f);
  u += 0x7fffu + ((u >> 16) & 1u);
  return (u16)(u >> 16);
}

__device__ __forceinline__ u32 cvtpk(float lo, float hi) {
  u32 r;
  asm("v_cvt_pk_bf16_f32 %0, %1, %2" : "=v"(r) : "v"(lo), "v"(hi));
  return r;
}

// Cross-half (lane ^ 32) combines -- PROVEN primitive (R3/R6 passed).
// Raw v_permlane32_swap asm failed both orientations (R4/R5); do not use.
// Struct-copy pipelining (R7) and dual-Q state (R9) spilled to scratch; do not use.
__device__ __forceinline__ float pr_max(float v) {
  return fmaxf(v, __shfl_xor(v, 32));
}
__device__ __forceinline__ float pr_add(float v) {
  return v + __shfl_xor(v, 32);
}

__device__ __forceinline__ float fexp2(float x) {
#if __has_builtin(__builtin_amdgcn_exp2f)
  return __builtin_amdgcn_exp2f(x);
#else
  return exp2f(x);
#endif
}

__device__ __forceinline__ f32x4 mfma16(short8 a, short8 b, f32x4 c) {
  return __builtin_amdgcn_mfma_f32_16x16x32_bf16(a, b, c, 0, 0, 0);
}
__device__ __forceinline__ f32x16 mfma32(short8 a, short8 b, f32x16 c) {
  return __builtin_amdgcn_mfma_f32_32x32x16_bf16(a, b, c, 0, 0, 0);
}

// pack 8 f32 P-values into one PV B-frag (k-slice), R3-proven mapping:
//   lower lane: {own w0, own w1, partner w0, partner w1}
//   upper lane: {partner w2, partner w3, own w2, own w3}
__device__ __forceinline__ short8 pack_frag(u32 w0, u32 w1, u32 w2, u32 w3, bool hi) {
  u32 x0 = (u32)__shfl_xor((int)w0, 32), x1 = (u32)__shfl_xor((int)w1, 32);
  u32 x2 = (u32)__shfl_xor((int)w2, 32), x3 = (u32)__shfl_xor((int)w3, 32);
  u32x4 f = { hi ? x2 : w0, hi ? x3 : w1, hi ? w2 : x0, hi ? w3 : x1 };
  return __builtin_bit_cast(short8, f);
}

// ---------------- conversion / transpose kernels ----------------

__global__ void k_conv_x(const float* __restrict__ x, u16* __restrict__ xb, int n) {
  int i = blockIdx.x * 256 + threadIdx.x;
  if (i < n) xb[i] = f2bf(x[i]);
}

__global__ __launch_bounds__(256) void k_transpose_w(const float* __restrict__ w,
                                                     u16* __restrict__ wt,
                                                     int rows, int cols) {
  __shared__ float tile[32][33];
  int tx = threadIdx.x & 31, ty = threadIdx.x >> 5;
  int kb = blockIdx.x * 32;
  int nb = blockIdx.y * 32;
#pragma unroll
  for (int j = 0; j < 4; j++)
    tile[ty + 8 * j][tx] = w[(size_t)(kb + ty + 8 * j) * cols + nb + tx];
  __syncthreads();
#pragma unroll
  for (int j = 0; j < 4; j++)
    wt[(size_t)(nb + ty + 8 * j) * rows + kb + tx] = f2bf(tile[tx][ty + 8 * j]);
}

// ---------------- QKV GEMM + bias + RoPE epilogue ----------------
__global__ __launch_bounds__(256) void k_qkv(const u16* __restrict__ A,
                                             const u16* __restrict__ Bt,
                                             const float* __restrict__ bias,
                                             u16* __restrict__ Qb,
                                             u16* __restrict__ Kb,
                                             u16* __restrict__ Vt) {
  __shared__ u16 As[128][40];
  __shared__ u16 Bs[128][40];
  int t = threadIdx.x;
  int w = t >> 6, lane = t & 63, g = lane >> 4, c = lane & 15;
  int wr = w >> 1, wc = w & 1;
  int bm = blockIdx.x * 128, bn = blockIdx.y * 128;

  f32x4 acc[4][4];
#pragma unroll
  for (int m = 0; m < 4; m++)
#pragma unroll
    for (int n = 0; n < 4; n++) acc[m][n] = (f32x4){0.f, 0.f, 0.f, 0.f};

  int srow = t >> 1, sseg = (t & 1) * 16;
  for (int bk = 0; bk < EMB; bk += 32) {
    const u16* ga = A  + (size_t)(bm + srow) * EMB + bk + sseg;
    const u16* gb = Bt + (size_t)(bn + srow) * EMB + bk + sseg;
    short8 a0 = *(const short8*)ga, a1 = *(const short8*)(ga + 8);
    short8 b0 = *(const short8*)gb, b1 = *(const short8*)(gb + 8);
    __syncthreads();
    *(short8*)&As[srow][sseg] = a0; *(short8*)&As[srow][sseg + 8] = a1;
    *(short8*)&Bs[srow][sseg] = b0; *(short8*)&Bs[srow][sseg + 8] = b1;
    __syncthreads();
    short8 af[4], bf[4];
#pragma unroll
    for (int m = 0; m < 4; m++) af[m] = *(const short8*)&As[wr * 64 + m * 16 + c][g * 8];
#pragma unroll
    for (int n = 0; n < 4; n++) bf[n] = *(const short8*)&Bs[wc * 64 + n * 16 + c][g * 8];
#pragma unroll
    for (int m = 0; m < 4; m++)
#pragma unroll
      for (int n = 0; n < 4; n++) acc[m][n] = mfma16(af[m], bf[n], acc[m][n]);
  }

  int colbase = bn + wc * 64;
  int sec = colbase / EMB;               // 0=Q 1=K 2=V
  int hh  = (colbase % EMB) / DH;
  float qs = (sec == 0) ? QSCALE : 1.0f;
  float invf[2];
#pragma unroll
  for (int n = 0; n < 2; n++) {
    int d1 = n * 16 + c;
    invf[n] = exp2f(-(float)d1 * (13.287712379549449f / 32.0f));
  }
#pragma unroll
  for (int m = 0; m < 4; m++) {
    int rowb = bm + wr * 64 + m * 16 + 4 * g;
#pragma unroll
    for (int e = 0; e < 4; e++) {
      int srw = rowb + e;
      float v[4];
#pragma unroll
      for (int n = 0; n < 4; n++) v[n] = acc[m][n][e] + bias[colbase + n * 16 + c];
      if (sec == 2) {
#pragma unroll
        for (int n = 0; n < 4; n++)
          Vt[(size_t)(hh * DH + n * 16 + c) * S_LEN + srw] = f2bf(v[n]);
      } else {
        u16* dst = (sec == 0) ? Qb : Kb;
        size_t base = ((size_t)hh * S_LEN + srw) * DH;
#pragma unroll
        for (int n = 0; n < 2; n++) {
          int d1 = n * 16 + c;
          float ang = (float)srw * invf[n];
          float sn, cs;
          sincosf(ang, &sn, &cs);
          float o1 = (v[n] * cs - v[n + 2] * sn) * qs;
          float o2 = (v[n + 2] * cs + v[n] * sn) * qs;
          dst[base + d1]      = f2bf(o1);
          dst[base + d1 + 32] = f2bf(o2);
        }
      }
    }
  }
}

// ---------------- flash attention ----------------
// 384 blocks x 4 waves. Block owns 128 q-rows (wave w: rows sb*128+w*32..+32)
// of one head and iterates the shared causal KV range once. Per tile the whole
// block cooperatively reg-stages K(32x64)+V(64x32) into padded LDS, double-
// buffered, ONE barrier per tile: stage loads issue at top (latency hidden
// under compute), ds_write targets the other buffer. Waves compute their rows
// from LDS; no cross-wave merge needed.

__device__ __forceinline__ f32x16 qk4(short8 k0, short8 k1, short8 k2, short8 k3,
                                      short8 q0, short8 q1, short8 q2, short8 q3) {
  f32x16 sc = {0,0,0,0,0,0,0,0,0,0,0,0,0,0,0,0};
  __builtin_amdgcn_s_setprio(1);
  sc = mfma32(k0, q0, sc);
  sc = mfma32(k1, q1, sc);
  sc = mfma32(k2, q2, sc);
  sc = mfma32(k3, q3, sc);
  __builtin_amdgcn_s_setprio(0);
  return sc;
}

__device__ __forceinline__ void finish_set(f32x16 sc, bool masked, int qi, int half,
    short8 v0, short8 v1, short8 v2, short8 v3,
    f32x16& acc0, f32x16& acc1, float& m, float& l) {
  if (masked) {
#pragma unroll
    for (int i = 0; i < 16; i++) {
      int kl = (i & 3) + 8 * (i >> 2) + 4 * half;
      if (kl > qi) sc[i] = -1e30f;
    }
  }
  float t0 = fmaxf(fmaxf(sc[0], sc[1]), fmaxf(sc[2], sc[3]));
  float t1 = fmaxf(fmaxf(sc[4], sc[5]), fmaxf(sc[6], sc[7]));
  float t2 = fmaxf(fmaxf(sc[8], sc[9]), fmaxf(sc[10], sc[11]));
  float t3 = fmaxf(fmaxf(sc[12], sc[13]), fmaxf(sc[14], sc[15]));
  float rmax = pr_max(fmaxf(fmaxf(t0, t1), fmaxf(t2, t3)));
  if (__any(rmax > m + 8.0f)) {
    float mn = fmaxf(m, rmax);
    float f = fexp2(m - mn);
    m = mn; l *= f;
#pragma unroll
    for (int i = 0; i < 16; i++) { acc0[i] *= f; acc1[i] *= f; }
  }
  f32x16 p;
#pragma unroll
  for (int i = 0; i < 16; i++) p[i] = fexp2(sc[i] - m);
  l += ((p[0] + p[1]) + (p[2] + p[3])) + ((p[4] + p[5]) + (p[6] + p[7]))
     + ((p[8] + p[9]) + (p[10] + p[11])) + ((p[12] + p[13]) + (p[14] + p[15]));
  bool hi = (half != 0);
  short8 pa0 = pack_frag(cvtpk(p[0], p[1]),   cvtpk(p[2], p[3]),
                         cvtpk(p[4], p[5]),   cvtpk(p[6], p[7]), hi);
  short8 pa1 = pack_frag(cvtpk(p[8], p[9]),   cvtpk(p[10], p[11]),
                         cvtpk(p[12], p[13]), cvtpk(p[14], p[15]), hi);
  __builtin_amdgcn_s_setprio(1);
  acc0 = mfma32(v0, pa0, acc0);
  acc0 = mfma32(v1, pa1, acc0);
  acc1 = mfma32(v2, pa0, acc1);
  acc1 = mfma32(v3, pa1, acc1);
  __builtin_amdgcn_s_setprio(0);
}

__global__ __launch_bounds__(256, 3) void k_attn(const u16* __restrict__ Q,
                                                 const u16* __restrict__ K,
                                                 const u16* __restrict__ Vt,
                                                 u16* __restrict__ O) {
  // padded, 16B-aligned rows: K rows 72 u16 (144B), V rows 40 u16 (80B)
  __shared__ __align__(16) u16 KL[2][32][72];
  __shared__ __align__(16) u16 VL[2][64][40];

  int t = threadIdx.x;
  int w = t >> 6, lane = t & 63;
  int qi = lane & 31, half = lane >> 5;
  int b = blockIdx.x;
  int j = b / NH, h = b - j * NH;
  // long/short alternation: pairs (31-k, k) sum to constant work
  int sb = (j & 1) ? (j >> 1) : (31 - (j >> 1));

  const u16* Kh = K  + (size_t)h * S_LEN * DH;
  const u16* Vh = Vt + (size_t)h * DH * S_LEN;

  int qrow = sb * 128 + w * 32 + qi;
  const u16* qp = Q + ((size_t)h * S_LEN + qrow) * DH + half * 8;
  short8 qf0 = *(const short8*)(qp);
  short8 qf1 = *(const short8*)(qp + 16);
  short8 qf2 = *(const short8*)(qp + 32);
  short8 qf3 = *(const short8*)(qp + 48);

  int diag = 4 * sb + w;               // wave's last (masked) tile
  int nt   = 4 * sb + 4;               // tiles staged by the block

  // staging assignment (256 threads)
  int krow = t >> 3, kseg = t & 7;     // K: 32 rows x 8 chunks
  int vrow = t >> 2, vseg = t & 3;     // V: 64 rows x 4 chunks
  const u16* kg = Kh + (size_t)krow * DH + kseg * 8;
  const u16* vg = Vh + (size_t)vrow * S_LEN + vseg * 8;

  // prologue: stage tile 0 into buf 0
  {
    short8 ks = *(const short8*)(kg);
    short8 vs = *(const short8*)(vg);
    *(short8*)&KL[0][krow][kseg * 8] = ks;
    *(short8*)&VL[0][vrow][vseg * 8] = vs;
  }
  __syncthreads();

  f32x16 acc0 = {0,0,0,0,0,0,0,0,0,0,0,0,0,0,0,0};
  f32x16 acc1 = {0,0,0,0,0,0,0,0,0,0,0,0,0,0,0,0};
  float m = -1e30f, l = 0.f;

  int cur = 0;
#pragma unroll 1
  for (int tt = 0; tt < nt; tt++) {
    bool more = (tt + 1 < nt);
    short8 kn, vn;
    if (more) {                         // issue next-tile global loads early
      kn = *(const short8*)(kg + (size_t)(tt + 1) * 32 * DH);
      vn = *(const short8*)(vg + (tt + 1) * 32);
    }
    if (tt <= diag) {                   // wave-uniform
      short8 k0 = *(const short8*)&KL[cur][qi][half * 8];
      short8 k1 = *(const short8*)&KL[cur][qi][half * 8 + 16];
      short8 k2 = *(const short8*)&KL[cur][qi][half * 8 + 32];
      short8 k3 = *(const short8*)&KL[cur][qi][half * 8 + 48];
      f32x16 sc = qk4(k0, k1, k2, k3, qf0, qf1, qf2, qf3);
      short8 v0 = *(const short8*)&VL[cur][qi][half * 8];
      short8 v1 = *(const short8*)&VL[cur][qi][half * 8 + 16];
      short8 v2 = *(const short8*)&VL[cur][32 + qi][half * 8];
      short8 v3 = *(const short8*)&VL[cur][32 + qi][half * 8 + 16];
      finish_set(sc, tt == diag, qi, half, v0, v1, v2, v3, acc0, acc1, m, l);
    }
    if (more) {                         // write to OTHER buffer (no race)
      *(short8*)&KL[cur ^ 1][krow][kseg * 8] = kn;
      *(short8*)&VL[cur ^ 1][vrow][vseg * 8] = vn;
    }
    __syncthreads();
    cur ^= 1;
  }

  // per-wave epilogue (each wave owns its 32 rows; no merge)
  float lrow = pr_add(l);
  float rl = 1.0f / lrow;
  u16* orow = O + (size_t)qrow * EMB + h * DH;
#pragma unroll
  for (int i = 0; i < 16; i += 2) {
    int dl = (i & 3) + 8 * (i >> 2) + 4 * half;
    u32 wa = cvtpk(acc0[i] * rl, acc0[i + 1] * rl);
    u32 wb = cvtpk(acc1[i] * rl, acc1[i + 1] * rl);
    *(u32*)(orow + dl)      = wa;
    *(u32*)(orow + 32 + dl) = wb;
  }
}

// ---------------- output projection ----------------
__global__ __launch_bounds__(256) void k_out(const u16* __restrict__ A,
                                             const u16* __restrict__ Bt,
                                             const float* __restrict__ bias,
                                             float* __restrict__ out) {
  __shared__ u16 As[128][40];
  __shared__ u16 Bs[128][40];
  int t = threadIdx.x;
  int w = t >> 6, lane = t & 63, g = lane >> 4, c = lane & 15;
  int wr = w >> 1, wc = w & 1;
  int bm = blockIdx.x * 128, bn = blockIdx.y * 128;

  f32x4 acc[4][4];
#pragma unroll
  for (int m = 0; m < 4; m++)
#pragma unroll
    for (int n = 0; n < 4; n++) acc[m][n] = (f32x4){0.f, 0.f, 0.f, 0.f};

  int srow = t >> 1, sseg = (t & 1) * 16;
  for (int bk = 0; bk < EMB; bk += 32) {
    const u16* ga = A  + (size_t)(bm + srow) * EMB + bk + sseg;
    const u16* gb = Bt + (size_t)(bn + srow) * EMB + bk + sseg;
    short8 a0 = *(const short8*)ga, a1 = *(const short8*)(ga + 8);
    short8 b0 = *(const short8*)gb, b1 = *(const short8*)(gb + 8);
    __syncthreads();
    *(short8*)&As[srow][sseg] = a0; *(short8*)&As[srow][sseg + 8] = a1;
    *(short8*)&Bs[srow][sseg] = b0; *(short8*)&Bs[srow][sseg + 8] = b1;
    __syncthreads();
    short8 af[4], bf[4];
#pragma unroll
    for (int m = 0; m < 4; m++) af[m] = *(const short8*)&As[wr * 64 + m * 16 + c][g * 8];
#pragma unroll
    for (int n = 0; n < 4; n++) bf[n] = *(const short8*)&Bs[wc * 64 + n * 16 + c][g * 8];
#pragma unroll
    for (int m = 0; m < 4; m++)
#pragma unroll
      for (int n = 0; n < 4; n++) acc[m][n] = mfma16(af[m], bf[n], acc[m][n]);
  }
  int colbase = bn + wc * 64;
#pragma unroll
  for (int m = 0; m < 4; m++) {
    int rowb = bm + wr * 64 + m * 16 + 4 * g;
#pragma unroll
    for (int e = 0; e < 4; e++) {
      int srw = rowb + e;
#pragma unroll
      for (int n = 0; n < 4; n++) {
        int col = colbase + n * 16 + c;
        out[(size_t)srw * EMB + col] = acc[m][n][e] + bias[col];
      }
    }
  }
}

// ---------------- launcher ----------------

extern "C" void kernel_launch(void* const* d_in, const int* in_sizes, int n_in,
                              void* d_out, int out_size, void* d_ws, size_t ws_size,
                              hipStream_t stream) {
  const float* x    = (const float*)d_in[0];
  const float* Wqkv = (const float*)d_in[2];
  const float* bqkv = (const float*)d_in[3];
  const float* Wout = (const float*)d_in[4];
  const float* bout = (const float*)d_in[5];
  float* out = (float*)d_out;

  char* ws = (char*)d_ws;
  u16* xb     = (u16*)(ws);
  u16* wqkvt  = (u16*)(ws + 6291456);
  u16* woutt  = (u16*)(ws + 9830400);
  u16* Qb     = (u16*)(ws + 11010048);
  u16* Kb     = (u16*)(ws + 17301504);
  u16* Vtb    = (u16*)(ws + 23592960);
  u16* Ob     = (u16*)(ws + 29884416);

  k_conv_x<<<(S_LEN * EMB + 255) / 256, 256, 0, stream>>>(x, xb, S_LEN * EMB);
  k_transpose_w<<<dim3(EMB / 32, 3 * EMB / 32), 256, 0, stream>>>(Wqkv, wqkvt, EMB, 3 * EMB);
  k_transpose_w<<<dim3(EMB / 32, EMB / 32), 256, 0, stream>>>(Wout, woutt, EMB, EMB);

  k_qkv<<<dim3(32, 18), 256, 0, stream>>>(xb, wqkvt, bqkv, Qb, Kb, Vtb);
  k_attn<<<384, 256, 0, stream>>>(Qb, Kb, Vtb, Ob);
  k_out<<<dim3(32, 6), 256, 0, stream>>>(Ob, woutt, bout, out);
}